// Round 8
// baseline (117.249 us; speedup 1.0000x reference)
//
#include <hip/hip_runtime.h>

#define B_ 4
#define L_ 4096
#define D_ 64
#define N_ 16
#define CHUNK 16
#define NCHUNK (L_ / CHUNK)        // 256
#define TOTCHUNK (B_ * NCHUNK)     // 1024
#define PROW 48                    // P row: a[16] | g[16] | cm[16]

constexpr float DT_  = 0.1f;
constexpr float EPS_ = 1e-6f;

// ---------------------------------------------------------------------------
// K1: projections only. 1024 blocks x 64 threads. lane = (n = lane&15,
// qt = lane>>4). Each lane computes BOTH Bm[n] and Cm[n] over K-quarter
// qt*16..qt*16+15 (4 b128 reads/position instead of 8), combined with two
// shfl_xor — after which EVERY lane holds the full dots, so a/g/cm/cum/Wcor
// are computed redundantly in-register and the four lane-quarters write four
// different LDS buffers simultaneously. Outputs (global, coalesced float4
// blasts): P rows [a|g|cm] per position, Wcor, Cdec.
// ---------------------------------------------------------------------------
__global__ __launch_bounds__(64) void proj_kernel(
    const float* __restrict__ x,  const float* __restrict__ A,
    const float* __restrict__ Wb, const float* __restrict__ bb,
    const float* __restrict__ Wc, const float* __restrict__ bc,
    const float* __restrict__ Wd, const float* __restrict__ bd,
    float* __restrict__ P, float* __restrict__ Wcor, float* __restrict__ Cdec)
{
    const int gc    = blockIdx.x;              // global chunk 0..1023
    const int batch = gc >> 8;
    const int c     = gc & (NCHUNK - 1);
    const int lane  = threadIdx.x;
    const int base0 = batch * L_ + c * CHUNK;

    __shared__ float xs[CHUNK * D_];           // 4 KB
    __shared__ float pbuf[CHUNK * PROW];       // 3 KB  (a|g|cm rows)
    __shared__ float wbuf[CHUNK * N_];         // 1 KB  (Wcor rows)

    // ---- stage chunk's x ----
    const float4* xg  = (const float4*)(x + (size_t)base0 * D_);
    float4*       xsv = (float4*)xs;
    #pragma unroll
    for (int i = 0; i < 4; i++) xsv[i * 64 + lane] = xg[i * 64 + lane];

    // ---- W quarter-rows in registers (both Bm and Cm rows for this n) ----
    const int n  = lane & 15;
    const int qt = lane >> 4;                  // K-quarter 0..3
    float wB[16], wC[16];
    {
        const float4* wb4 = (const float4*)(Wb + n * D_ + qt * 16);
        const float4* wc4 = (const float4*)(Wc + n * D_ + qt * 16);
        #pragma unroll
        for (int j = 0; j < 4; j++) {
            float4 b4 = wb4[j], c4 = wc4[j];
            wB[4*j+0] = b4.x; wB[4*j+1] = b4.y; wB[4*j+2] = b4.z; wB[4*j+3] = b4.w;
            wC[4*j+0] = c4.x; wC[4*j+1] = c4.y; wC[4*j+2] = c4.z; wC[4*j+3] = c4.w;
        }
    }
    const float wd  = Wd[lane];
    const float bd0 = bd[0];
    const float An  = A[n];                    // row 0 of (D,N); rows identical
    const float bB  = bb[n];
    const float bC  = bc[n];

    __syncthreads();

    // ---- deltas: 16 butterflies over all 64 lanes, interleaved ----
    float r[CHUNK];
    #pragma unroll
    for (int p = 0; p < CHUNK; p++) r[p] = xs[p * D_ + lane] * wd;
    #pragma unroll
    for (int m = 32; m >= 1; m >>= 1) {
        #pragma unroll
        for (int p = 0; p < CHUNK; p++) r[p] += __shfl_xor(r[p], m, 64);
    }
    float delta[CHUNK];
    #pragma unroll
    for (int p = 0; p < CHUNK; p++) {
        float z = r[p] + bd0;
        delta[p] = fmaxf(z, 0.0f) + log1pf(expf(-fabsf(z))) + DT_;
    }

    // ---- quarter-split dots; every lane ends with full Bm[n], Cm[n] ----
    float av[CHUNK], cv[CHUNK];
    #pragma unroll
    for (int p = 0; p < CHUNK; p++) {
        const float4* xs4 = (const float4*)(xs + p * D_ + qt * 16);
        float accB = 0.0f, accC = 0.0f;
        #pragma unroll
        for (int j = 0; j < 4; j++) {
            float4 v = xs4[j];                 // 4-address broadcast read
            accB += v.x * wB[4*j+0] + v.y * wB[4*j+1] + v.z * wB[4*j+2] + v.w * wB[4*j+3];
            accC += v.x * wC[4*j+0] + v.y * wC[4*j+1] + v.z * wC[4*j+2] + v.w * wC[4*j+3];
        }
        accB += __shfl_xor(accB, 16, 64);  accB += __shfl_xor(accB, 32, 64);
        accC += __shfl_xor(accC, 16, 64);  accC += __shfl_xor(accC, 32, 64);

        float Bm  = accB + bB;
        float Cmv = accC + bC;
        float tmp = An * delta[p];
        float a   = expf(tmp);
        float g   = (a - 1.0f) * delta[p] * Bm / (tmp + EPS_);
        av[p] = a;  cv[p] = Cmv;
        // four quarters write four different targets in parallel
        if      (qt == 0) pbuf[p * PROW + n]      = a;
        else if (qt == 1) pbuf[p * PROW + 16 + n] = g;
        else if (qt == 2) pbuf[p * PROW + 32 + n] = Cmv;
    }

    // ---- cumulative decay, Wcor rows, chunk decay ----
    float cum = 1.0f;
    #pragma unroll
    for (int p = 0; p < CHUNK; p++) {
        cum *= av[p];
        if (qt == 3) wbuf[p * N_ + n] = cv[p] * cum;
    }
    if (qt == 3) Cdec[gc * N_ + n] = cum;
    __syncthreads();

    // ---- coalesced blasts to global ----
    {
        float4*       Pg  = (float4*)(P + (size_t)gc * (CHUNK * PROW)); // 192 f4
        const float4* pb4 = (const float4*)pbuf;
        Pg[lane]       = pb4[lane];
        Pg[64 + lane]  = pb4[64 + lane];
        Pg[128 + lane] = pb4[128 + lane];
        ((float4*)(Wcor + (size_t)gc * (CHUNK * N_)))[lane] = ((const float4*)wbuf)[lane];
    }
}

// ---------------------------------------------------------------------------
// K2: local scan + local output. 1024 blocks x 64 threads, ZERO LDS.
// Coefficients read as wave-uniform float4 global loads (scalarizable);
// x columns and out stores are per-lane coalesced. Inner loop is pure VALU.
// ---------------------------------------------------------------------------
__global__ __launch_bounds__(64) void scan_kernel(
    const float* __restrict__ x, const float* __restrict__ P,
    float* __restrict__ S, float* __restrict__ out)
{
    const int gc    = blockIdx.x;
    const int batch = gc >> 8;
    const int c     = gc & (NCHUNK - 1);
    const int lane  = threadIdx.x;             // = d
    const int base0 = batch * L_ + c * CHUNK;

    // x column for this lane (coalesced: 64 consecutive floats per position)
    float xq[CHUNK];
    #pragma unroll
    for (int p = 0; p < CHUNK; p++)
        xq[p] = x[(size_t)(base0 + p) * D_ + lane];

    const float* pp = P + (size_t)gc * (CHUNK * PROW);

    float h[N_];
    #pragma unroll
    for (int i = 0; i < N_; i++) h[i] = 0.0f;

    #pragma unroll
    for (int p = 0; p < CHUNK; p++) {
        const float4* row = (const float4*)(pp + p * PROW);  // uniform address
        float acc = 0.0f;
        #pragma unroll
        for (int q = 0; q < 4; q++) {
            float4 a4 = row[q];
            float4 g4 = row[4 + q];
            float4 c4 = row[8 + q];
            h[4*q+0] = a4.x * h[4*q+0] + g4.x * xq[p];  acc += c4.x * h[4*q+0];
            h[4*q+1] = a4.y * h[4*q+1] + g4.y * xq[p];  acc += c4.y * h[4*q+1];
            h[4*q+2] = a4.z * h[4*q+2] + g4.z * xq[p];  acc += c4.z * h[4*q+2];
            h[4*q+3] = a4.w * h[4*q+3] + g4.w * xq[p];  acc += c4.w * h[4*q+3];
        }
        out[(size_t)(base0 + p) * D_ + lane] = acc;          // local output
    }
    #pragma unroll
    for (int i = 0; i < N_; i++)
        S[(size_t)(gc * N_ + i) * D_ + lane] = h[i];         // chunk-final state
}

// ---------------------------------------------------------------------------
// K3: cross-chunk exclusive scan (frozen from R7). 64 blocks x 64 threads;
// block=(b,n), thread=d; groups of 32 with next-group prefetch.
// ---------------------------------------------------------------------------
#define G_ 32
__global__ __launch_bounds__(64) void combine(
    float* __restrict__ S, const float* __restrict__ Cdec)
{
    const int b = blockIdx.x >> 4;
    const int n = blockIdx.x & 15;
    const int d = threadIdx.x;
    const int cb = b * NCHUNK;

    float*       baseS = S    + (size_t)(cb * N_ + n) * D_ + d;
    const float* baseA = Cdec + cb * N_ + n;

    float run = 0.0f;
    float sbuf[G_], abuf[G_];
    #pragma unroll
    for (int j = 0; j < G_; j++) {
        sbuf[j] = baseS[(size_t)j * (N_ * D_)];
        abuf[j] = baseA[j * N_];
    }
    for (int cc = 0; cc < NCHUNK; cc += G_) {
        const int cn = (cc + G_ < NCHUNK) ? (cc + G_) : cc;   // last: dummy reload
        float t[G_], u[G_];
        #pragma unroll
        for (int j = 0; j < G_; j++) {
            t[j] = baseS[(size_t)(cn + j) * (N_ * D_)];
            u[j] = baseA[(cn + j) * N_];
        }
        #pragma unroll
        for (int j = 0; j < G_; j++) {
            baseS[(size_t)(cc + j) * (N_ * D_)] = run;        // exclusive prefix
            run = abuf[j] * run + sbuf[j];
        }
        #pragma unroll
        for (int j = 0; j < G_; j++) { sbuf[j] = t[j]; abuf[j] = u[j]; }
    }
}

// ---------------------------------------------------------------------------
// K4: apply correction: out[l,d] += sum_n Wcor_l[n] * init[n,d].
// 1024 blocks x 64 threads, ZERO LDS; Wcor via uniform float4 loads.
// ---------------------------------------------------------------------------
__global__ __launch_bounds__(64) void apply_kernel(
    const float* __restrict__ Wcor, const float* __restrict__ S,
    float* __restrict__ out)
{
    const int gc    = blockIdx.x;
    const int batch = gc >> 8;
    const int c     = gc & (NCHUNK - 1);
    const int lane  = threadIdx.x;             // = d
    const int base0 = batch * L_ + c * CHUNK;

    float hi[N_];
    #pragma unroll
    for (int i = 0; i < N_; i++)
        hi[i] = S[(size_t)(gc * N_ + i) * D_ + lane];

    const float* wrow = Wcor + (size_t)gc * (CHUNK * N_);
    #pragma unroll
    for (int p = 0; p < CHUNK; p++) {
        const float4* w4 = (const float4*)(wrow + p * N_);   // uniform address
        float acc = 0.0f;
        #pragma unroll
        for (int q = 0; q < 4; q++) {
            float4 w = w4[q];
            acc += w.x * hi[4*q+0] + w.y * hi[4*q+1]
                 + w.z * hi[4*q+2] + w.w * hi[4*q+3];
        }
        const size_t idx = (size_t)(base0 + p) * D_ + lane;
        out[idx] = out[idx] + acc;
    }
}

// ---------------------------------------------------------------------------
extern "C" void kernel_launch(void* const* d_in, const int* in_sizes, int n_in,
                              void* d_out, int out_size, void* d_ws, size_t ws_size,
                              hipStream_t stream)
{
    const float* x  = (const float*)d_in[0];
    const float* A  = (const float*)d_in[1];
    const float* Wb = (const float*)d_in[2];
    const float* bb = (const float*)d_in[3];
    const float* Wc = (const float*)d_in[4];
    const float* bc = (const float*)d_in[5];
    const float* Wd = (const float*)d_in[6];
    const float* bd = (const float*)d_in[7];
    float* out = (float*)d_out;

    // ws carve (floats): P 786432 | Wcor 262144 | S 1048576 | Cdec 16384  (~8.3 MB)
    float* P    = (float*)d_ws;
    float* Wcor = P    + (size_t)TOTCHUNK * CHUNK * PROW;
    float* S    = Wcor + (size_t)TOTCHUNK * CHUNK * N_;
    float* Cdec = S    + (size_t)TOTCHUNK * N_ * D_;

    proj_kernel<<<TOTCHUNK, 64, 0, stream>>>(x, A, Wb, bb, Wc, bc, Wd, bd,
                                             P, Wcor, Cdec);
    scan_kernel<<<TOTCHUNK, 64, 0, stream>>>(x, P, S, out);
    combine<<<B_ * N_, 64, 0, stream>>>(S, Cdec);
    apply_kernel<<<TOTCHUNK, 64, 0, stream>>>(Wcor, S, out);
}

// Round 9
// 105.255 us; speedup vs baseline: 1.1140x; 1.1140x over previous
//
#include <hip/hip_runtime.h>

#define B_ 4
#define L_ 4096
#define D_ 64
#define N_ 16
#define CHUNK 16
#define NCHUNK (L_ / CHUNK)        // 256
#define TOTCHUNK (B_ * NCHUNK)     // 1024

constexpr float DT_  = 0.1f;
constexpr float EPS_ = 1e-6f;

// ---------------------------------------------------------------------------
// K1: fused projection + local chunk scan + local output + correction matrix.
// 1024 blocks x 64 threads (1 wave). lane = (n = lane&15, qt = lane>>4).
//
// Projection phase (quarter-split, fused delta): each lane accumulates
// Bm[n], Cm[n] AND the delta-dot over K-quarter qt*16..+15 from ONE pass over
// xs (4 b128 reads/position), then 6 shfl_xor combine all three. Every lane
// then owns a/g/cm for its n across all 16 positions in REGISTERS; the four
// lane-quarters write the a / g / cm LDS staging buffers in parallel, and
// qt==3 lanes compute Wcor (c_p * cumprod a) + Cdec entirely in-register.
//
// Scan phase (lane = d, frozen from R7): LDS-only broadcast reads of a/g/cm,
// zero-init scan, local output straight to out, chunk-final state -> S.
// ---------------------------------------------------------------------------
__global__ __launch_bounds__(64) void proj_scan_kernel(
    const float* __restrict__ x,  const float* __restrict__ A,
    const float* __restrict__ Wb, const float* __restrict__ bb,
    const float* __restrict__ Wc, const float* __restrict__ bc,
    const float* __restrict__ Wd, const float* __restrict__ bd,
    float* __restrict__ S, float* __restrict__ Cdec,
    float* __restrict__ Wcor, float* __restrict__ out)
{
    const int gc    = blockIdx.x;              // global chunk 0..1023
    const int batch = gc >> 8;
    const int c     = gc & (NCHUNK - 1);
    const int lane  = threadIdx.x;
    const int base0 = batch * L_ + c * CHUNK;

    __shared__ float xs[CHUNK * D_];           // 4 KB
    __shared__ float ag[CHUNK * 32];           // 2 KB  (a[16] | g[16] rows)
    __shared__ float cm[CHUNK * N_];           // 1 KB
    __shared__ float wbuf[CHUNK * N_];         // 1 KB  (Wcor rows)

    // ---- stage chunk's x ----
    const float4* xg  = (const float4*)(x + (size_t)base0 * D_);
    float4*       xsv = (float4*)xs;
    #pragma unroll
    for (int i = 0; i < 4; i++) xsv[i * 64 + lane] = xg[i * 64 + lane];

    // ---- W quarter-rows in registers (Bm row, Cm row, delta row) ----
    const int n  = lane & 15;
    const int qt = lane >> 4;                  // K-quarter 0..3
    float wB[16], wC[16], wD[16];
    {
        const float4* wb4 = (const float4*)(Wb + n * D_ + qt * 16);
        const float4* wc4 = (const float4*)(Wc + n * D_ + qt * 16);
        const float4* wd4 = (const float4*)(Wd + qt * 16);
        #pragma unroll
        for (int j = 0; j < 4; j++) {
            float4 b4 = wb4[j], c4 = wc4[j], d4 = wd4[j];
            wB[4*j+0] = b4.x; wB[4*j+1] = b4.y; wB[4*j+2] = b4.z; wB[4*j+3] = b4.w;
            wC[4*j+0] = c4.x; wC[4*j+1] = c4.y; wC[4*j+2] = c4.z; wC[4*j+3] = c4.w;
            wD[4*j+0] = d4.x; wD[4*j+1] = d4.y; wD[4*j+2] = d4.z; wD[4*j+3] = d4.w;
        }
    }
    const float bd0 = bd[0];
    const float An  = A[n];                    // row 0 of (D,N); rows identical
    const float bB  = bb[n];
    const float bC  = bc[n];

    __syncthreads();

    // ---- quarter-split dots, delta fused; coefficients into LDS + regs ----
    float av[CHUNK], cv[CHUNK];
    #pragma unroll
    for (int p = 0; p < CHUNK; p++) {
        const float4* xs4 = (const float4*)(xs + p * D_ + qt * 16);
        float accB = 0.0f, accC = 0.0f, accD = 0.0f;
        #pragma unroll
        for (int j = 0; j < 4; j++) {
            float4 v = xs4[j];                 // 4-address broadcast read
            accB += v.x * wB[4*j+0] + v.y * wB[4*j+1] + v.z * wB[4*j+2] + v.w * wB[4*j+3];
            accC += v.x * wC[4*j+0] + v.y * wC[4*j+1] + v.z * wC[4*j+2] + v.w * wC[4*j+3];
            accD += v.x * wD[4*j+0] + v.y * wD[4*j+1] + v.z * wD[4*j+2] + v.w * wD[4*j+3];
        }
        accB += __shfl_xor(accB, 16, 64);  accB += __shfl_xor(accB, 32, 64);
        accC += __shfl_xor(accC, 16, 64);  accC += __shfl_xor(accC, 32, 64);
        accD += __shfl_xor(accD, 16, 64);  accD += __shfl_xor(accD, 32, 64);

        float z     = accD + bd0;
        float delta = fmaxf(z, 0.0f) + log1pf(expf(-fabsf(z))) + DT_;
        float Bm    = accB + bB;
        float Cmv   = accC + bC;
        float tmp   = An * delta;
        float a     = expf(tmp);
        float g     = (a - 1.0f) * delta * Bm / (tmp + EPS_);
        av[p] = a;  cv[p] = Cmv;
        // four quarters write three different LDS targets in parallel
        if      (qt == 0) ag[p * 32 + n]      = a;
        else if (qt == 1) ag[p * 32 + 16 + n] = g;
        else if (qt == 2) cm[p * 16 + n]      = Cmv;
    }

    // ---- Wcor + Cdec entirely in-register (qt==3 lanes) ----
    {
        float cum = 1.0f;
        #pragma unroll
        for (int p = 0; p < CHUNK; p++) {
            cum *= av[p];
            if (qt == 3) wbuf[p * N_ + n] = cv[p] * cum;
        }
        if (qt == 3) Cdec[gc * N_ + n] = cum;
    }
    __syncthreads();

    // ---- coalesced blast of wbuf -> global Wcor (256 floats = 64 float4) ---
    ((float4*)(Wcor + (size_t)gc * (CHUNK * N_)))[lane] = ((const float4*)wbuf)[lane];

    // ---- local scan (zero init) + local output, LDS-only (frozen R7) ----
    float h[N_];
    #pragma unroll
    for (int i = 0; i < N_; i++) h[i] = 0.0f;
    for (int s = 0; s < CHUNK; s++) {
        float xd = xs[s * D_ + lane];
        const float4* row = (const float4*)(ag + s * 32);
        const float4* crw = (const float4*)(cm + s * 16);
        float acc = 0.0f;
        #pragma unroll
        for (int q = 0; q < 4; q++) {
            float4 a4 = row[q];
            float4 g4 = row[4 + q];
            float4 c4 = crw[q];
            h[4*q+0] = a4.x * h[4*q+0] + g4.x * xd;  acc += c4.x * h[4*q+0];
            h[4*q+1] = a4.y * h[4*q+1] + g4.y * xd;  acc += c4.y * h[4*q+1];
            h[4*q+2] = a4.z * h[4*q+2] + g4.z * xd;  acc += c4.z * h[4*q+2];
            h[4*q+3] = a4.w * h[4*q+3] + g4.w * xd;  acc += c4.w * h[4*q+3];
        }
        out[(size_t)(base0 + s) * D_ + lane] = acc;   // local (zero-init) output
    }
    #pragma unroll
    for (int i = 0; i < N_; i++)
        S[(size_t)(gc * N_ + i) * D_ + lane] = h[i];  // chunk-final local state
}

// ---------------------------------------------------------------------------
// K2: cross-chunk exclusive scan (frozen from R7). 64 blocks x 64 threads;
// block=(b,n), thread=d; groups of 32 with next-group prefetch.
// ---------------------------------------------------------------------------
#define G_ 32
__global__ __launch_bounds__(64) void combine(
    float* __restrict__ S, const float* __restrict__ Cdec)
{
    const int b = blockIdx.x >> 4;
    const int n = blockIdx.x & 15;
    const int d = threadIdx.x;
    const int cb = b * NCHUNK;

    float*       baseS = S    + (size_t)(cb * N_ + n) * D_ + d;
    const float* baseA = Cdec + cb * N_ + n;

    float run = 0.0f;
    float sbuf[G_], abuf[G_];
    #pragma unroll
    for (int j = 0; j < G_; j++) {
        sbuf[j] = baseS[(size_t)j * (N_ * D_)];
        abuf[j] = baseA[j * N_];
    }
    for (int cc = 0; cc < NCHUNK; cc += G_) {
        const int cn = (cc + G_ < NCHUNK) ? (cc + G_) : cc;   // last: dummy reload
        float t[G_], u[G_];
        #pragma unroll
        for (int j = 0; j < G_; j++) {
            t[j] = baseS[(size_t)(cn + j) * (N_ * D_)];
            u[j] = baseA[(cn + j) * N_];
        }
        #pragma unroll
        for (int j = 0; j < G_; j++) {
            baseS[(size_t)(cc + j) * (N_ * D_)] = run;        // exclusive prefix
            run = abuf[j] * run + sbuf[j];
        }
        #pragma unroll
        for (int j = 0; j < G_; j++) { sbuf[j] = t[j]; abuf[j] = u[j]; }
    }
}

// ---------------------------------------------------------------------------
// K3: apply correction: out[l,d] += sum_n Wcor_l[n] * init[n,d].
// (frozen from R7, dead code removed). 1024 blocks x 64 threads.
// ---------------------------------------------------------------------------
__global__ __launch_bounds__(64) void apply_kernel(
    const float* __restrict__ Wcor, const float* __restrict__ S,
    float* __restrict__ out)
{
    const int gc    = blockIdx.x;
    const int batch = gc >> 8;
    const int c     = gc & (NCHUNK - 1);
    const int lane  = threadIdx.x;             // = d
    const int base0 = batch * L_ + c * CHUNK;

    __shared__ float wl[CHUNK * N_];           // 1 KB

    // stage correction matrix (256 floats = 64 float4, one per lane)
    ((float4*)wl)[lane] = ((const float4*)(Wcor + (size_t)gc * (CHUNK * N_)))[lane];

    // chunk-initial state (post-combine S)
    float hi[N_];
    #pragma unroll
    for (int i = 0; i < N_; i++)
        hi[i] = S[(size_t)(gc * N_ + i) * D_ + lane];

    __syncthreads();

    #pragma unroll
    for (int p = 0; p < CHUNK; p++) {
        const float4* crw = (const float4*)(wl + p * N_);
        float acc = 0.0f;
        #pragma unroll
        for (int q = 0; q < 4; q++) {
            float4 w4 = crw[q];
            acc += w4.x * hi[4*q+0] + w4.y * hi[4*q+1]
                 + w4.z * hi[4*q+2] + w4.w * hi[4*q+3];
        }
        const size_t idx = (size_t)(base0 + p) * D_ + lane;
        out[idx] = out[idx] + acc;
    }
}

// ---------------------------------------------------------------------------
extern "C" void kernel_launch(void* const* d_in, const int* in_sizes, int n_in,
                              void* d_out, int out_size, void* d_ws, size_t ws_size,
                              hipStream_t stream)
{
    const float* x  = (const float*)d_in[0];
    const float* A  = (const float*)d_in[1];
    const float* Wb = (const float*)d_in[2];
    const float* bb = (const float*)d_in[3];
    const float* Wc = (const float*)d_in[4];
    const float* bc = (const float*)d_in[5];
    const float* Wd = (const float*)d_in[6];
    const float* bd = (const float*)d_in[7];
    float* out = (float*)d_out;

    // ws carve (floats): S 1048576 (4MB) | Cdec 16384 | Wcor 262144 (1MB)
    float* S    = (float*)d_ws;
    float* Cdec = S    + (size_t)TOTCHUNK * N_ * D_;
    float* Wcor = Cdec + (size_t)TOTCHUNK * N_;

    proj_scan_kernel<<<TOTCHUNK, 64, 0, stream>>>(x, A, Wb, bb, Wc, bc, Wd, bd,
                                                  S, Cdec, Wcor, out);
    combine<<<B_ * N_, 64, 0, stream>>>(S, Cdec);
    apply_kernel<<<TOTCHUNK, 64, 0, stream>>>(Wcor, S, out);
}